// Round 1
// baseline (443.912 us; speedup 1.0000x reference)
//
#include <hip/hip_runtime.h>
#include <stdint.h>

#define CH 64
#define NPTS 500000
#define NTILE (NPTS / 32)      // 15625 point-tiles of 32
#define NSTEP 12
#define BLK 256
#define WPB (BLK / 64)         // waves per block

typedef float floatx16 __attribute__((ext_vector_type(16)));
typedef __bf16 bf16x8 __attribute__((ext_vector_type(8)));

// pack two fp32 into (bf16(even) | bf16(odd)<<16) by byte-perm truncation
__device__ __forceinline__ unsigned pk(float odd, float even) {
    return __builtin_amdgcn_perm(__float_as_uint(odd), __float_as_uint(even), 0x07060302u);
}
// top-16-bit truncation of x as a float (the "hi" bf16 part, exactly representable)
__device__ __forceinline__ float hif(float x) {
    return __uint_as_float(__float_as_uint(x) & 0xffff0000u);
}

struct U16 { unsigned a, b, c, d; };
__device__ __forceinline__ bf16x8 asb4(unsigned x0, unsigned x1, unsigned x2, unsigned x3) {
    U16 t{x0, x1, x2, x3};
    return __builtin_bit_cast(bf16x8, t);
}
__device__ __forceinline__ bf16x8 asbu4(uint4 v) {
    return __builtin_bit_cast(bf16x8, v);
}

// async global->LDS, 16B per lane; lds ptr must be wave-uniform (HW scatters +lane*16)
typedef __attribute__((address_space(3))) void lds_void;
typedef const __attribute__((address_space(1))) void gm_void;
__device__ __forceinline__ void gload_lds16(const void* g, void* l) {
    __builtin_amdgcn_global_load_lds((gm_void*)g, (lds_void*)l, 16, 0, 0);
}

// ---------------------------------------------------------------------------
// Prep kernel: W[step][k][c_out] -> bf16 hi/lo A-fragments with the bit2<->bit3
// column permutation, in lane-contiguous per-step 16 KB groups.
// flat uint4 idx = s*1024 + ((pl*2+mt)*4+q)*64 + lane
// ---------------------------------------------------------------------------
__global__ void prep_weights(const float* __restrict__ W0,
                             const float* __restrict__ W1,
                             const float* __restrict__ W2,
                             uint4* __restrict__ wsA) {
    const int g  = blockIdx.x * blockDim.x + threadIdx.x;   // 0..12287
    const int mp = g & 31;
    const int h  = (g >> 5) & 1;
    const int q  = (g >> 6) & 3;
    const int mt = (g >> 8) & 1;
    const int pl = (g >> 9) & 1;
    const int s  = g >> 10;
    const float* Wb = (s % 3 == 0) ? W0 : ((s % 3 == 1) ? W1 : W2);
    const float* Ws = Wb + (s / 3) * CH * CH;
    const int m   = mt * 32 + mp;
    const int col = (m & ~12) | ((m & 4) << 1) | ((m & 8) >> 1);  // swap bits 2,3
    unsigned o[4];
    #pragma unroll
    for (int d = 0; d < 4; ++d) {
        float e = Ws[(16 * q + 8 * h + 2 * d) * CH + col];
        float v = Ws[(16 * q + 8 * h + 2 * d + 1) * CH + col];
        if (pl) { e = e - hif(e); v = v - hif(v); }   // lo plane
        o[d] = pk(v, e);
    }
    wsA[g] = make_uint4(o[0], o[1], o[2], o[3]);
}

// ---------------------------------------------------------------------------
// Main kernel: one wave = 32 points, register-resident 12-GEMM chain.
// Weights double-buffered in LDS (2 x 16 KB), staged via global_load_lds,
// read as ds_read_b128. One barrier per step.
// launch_bounds(256,5): reg budget 102/wave so occupancy matches the LDS cap
// of 5 blocks/CU (20 waves). Step-0 B built in the prologue to cut peak VGPRs.
// ---------------------------------------------------------------------------
__global__ __launch_bounds__(BLK, 5) void mlp12_mfma(
    const float* __restrict__ feat,
    const uint4* __restrict__ wsA,
    const float* __restrict__ b0,
    const float* __restrict__ b1,
    const float* __restrict__ b2,
    float* __restrict__ out)
{
    __shared__ uint4 sA[2][1024];   // 2 x 16 KB weight-fragment buffers

    const int tid  = threadIdx.x;
    const int lane = tid & 63;
    const int wv   = tid >> 6;
    int wid = blockIdx.x * WPB + wv;
    if (wid > NTILE - 1) wid = NTILE - 1;   // tail waves redo last tile (benign, no divergence at barriers)
    const int n = lane & 31;       // point within tile (MFMA col)
    const int h = lane >> 5;       // half-wave = k/channel bit3
    const size_t row = (size_t)(wid * 32 + n) * CH;

    // stage step-0 fragments into sA[0]: each thread issues 4 x 16B DMA
    {
        const char* g = (const char*)wsA;
        #pragma unroll
        for (int c = 0; c < 4; ++c)
            gload_lds16(g + (wv * 4 + c) * 1024 + lane * 16,
                        (char*)&sA[0][0] + (wv * 4 + c) * 1024);
    }

    // build step-0 B fragments straight from the feature loads (per-q, short
    // liveness; VALU overlaps the staging DMA drain)
    unsigned Bhi[4][4], Blo[4][4];
    {
        const float* frow = feat + row + 8 * h;
        #pragma unroll
        for (int q = 0; q < 4; ++q) {
            float4 va = *(const float4*)(frow + 16 * q);
            float4 vb = *(const float4*)(frow + 16 * q + 4);
            Bhi[q][0] = pk(va.y, va.x);
            Bhi[q][1] = pk(va.w, va.z);
            Bhi[q][2] = pk(vb.y, vb.x);
            Bhi[q][3] = pk(vb.w, vb.z);
            Blo[q][0] = pk(va.y - hif(va.y), va.x - hif(va.x));
            Blo[q][1] = pk(va.w - hif(va.w), va.z - hif(va.z));
            Blo[q][2] = pk(vb.y - hif(vb.y), vb.x - hif(vb.x));
            Blo[q][3] = pk(vb.w - hif(vb.w), vb.z - hif(vb.z));
        }
    }
    __syncthreads();   // drains vmcnt -> sA[0] ready

    floatx16 acc0, acc1;

    #pragma unroll
    for (int s = 0; s < NSTEP; ++s) {
        const int b = s & 1;

        // prefetch step s+1 into the buffer freed by the previous barrier
        if (s + 1 < NSTEP) {
            const char* g = (const char*)wsA + (size_t)(s + 1) * 16384;
            #pragma unroll
            for (int c = 0; c < 4; ++c)
                gload_lds16(g + (wv * 4 + c) * 1024 + lane * 16,
                            (char*)&sA[1 - b][0] + (wv * 4 + c) * 1024);
        }

        const uint4* base = &sA[b][0];

        // issue first A chunk (q=0) early: ds_read latency hides under B-build VALU
        uint4 Acur[4], Anx[4];
        #pragma unroll
        for (int t = 0; t < 4; ++t) Acur[t] = base[(t * 4 + 0) * 64 + lane];

        // ---- build B fragments from prev accs (step 0 was built in prologue)
        if (s > 0) {
            const bool relu = (s % 3 == 2);  // prev step had ReLU
            #pragma unroll
            for (int q = 0; q < 4; ++q) {
                const int rr = q & 1;
                #pragma unroll
                for (int d = 0; d < 4; ++d) {
                    float e, o;
                    if (q < 2) { e = acc0[8 * rr + 2 * d]; o = acc0[8 * rr + 2 * d + 1]; }
                    else       { e = acc1[8 * rr + 2 * d]; o = acc1[8 * rr + 2 * d + 1]; }
                    if (relu) { e = fmaxf(e, 0.f); o = fmaxf(o, 0.f); }
                    Bhi[q][d] = pk(o, e);
                    Blo[q][d] = pk(o - hif(o), e - hif(e));
                }
            }
        }

        // ---- init accumulators with bias (loads L2-hit; short live range)
        {
            const float* bs = ((s % 3 == 0) ? b0 : (s % 3 == 1) ? b1 : b2) + (s / 3) * CH;
            #pragma unroll
            for (int rq = 0; rq < 4; ++rq) {
                const int off = 16 * (rq >> 1) + 8 * h + 4 * (rq & 1);
                float4 v0 = *(const float4*)(bs + off);
                float4 v1 = *(const float4*)(bs + 32 + off);
                acc0[4 * rq + 0] = v0.x; acc0[4 * rq + 1] = v0.y;
                acc0[4 * rq + 2] = v0.z; acc0[4 * rq + 3] = v0.w;
                acc1[4 * rq + 0] = v1.x; acc1[4 * rq + 1] = v1.y;
                acc1[4 * rq + 2] = v1.z; acc1[4 * rq + 3] = v1.w;
            }
        }

        // ---- 24 MFMAs: hi*hi + lo_w*hi_x + hi_w*lo_x; A chunks pipelined via LDS
        #pragma unroll
        for (int q = 0; q < 4; ++q) {
            if (q < 3) {
                #pragma unroll
                for (int t = 0; t < 4; ++t) Anx[t] = base[(t * 4 + q + 1) * 64 + lane];
            }
            bf16x8 bh = asb4(Bhi[q][0], Bhi[q][1], Bhi[q][2], Bhi[q][3]);
            bf16x8 bl = asb4(Blo[q][0], Blo[q][1], Blo[q][2], Blo[q][3]);
            __builtin_amdgcn_s_setprio(1);
            acc0 = __builtin_amdgcn_mfma_f32_32x32x16_bf16(asbu4(Acur[0]), bh, acc0, 0, 0, 0);
            acc1 = __builtin_amdgcn_mfma_f32_32x32x16_bf16(asbu4(Acur[1]), bh, acc1, 0, 0, 0);
            acc0 = __builtin_amdgcn_mfma_f32_32x32x16_bf16(asbu4(Acur[2]), bh, acc0, 0, 0, 0);
            acc1 = __builtin_amdgcn_mfma_f32_32x32x16_bf16(asbu4(Acur[3]), bh, acc1, 0, 0, 0);
            acc0 = __builtin_amdgcn_mfma_f32_32x32x16_bf16(asbu4(Acur[0]), bl, acc0, 0, 0, 0);
            acc1 = __builtin_amdgcn_mfma_f32_32x32x16_bf16(asbu4(Acur[1]), bl, acc1, 0, 0, 0);
            __builtin_amdgcn_s_setprio(0);
            #pragma unroll
            for (int t = 0; t < 4; ++t) Acur[t] = Anx[t];
        }

        __syncthreads();  // all waves done with sA[b]; prefetch of s+1 drained
    }

    // ---- store step-11 output; un-permute C row rho -> channel pi(rho)
    float* orow = out + row;
    #pragma unroll
    for (int rq = 0; rq < 4; ++rq) {
        float4 v0, v1;
        v0.x = acc0[4 * rq + 0]; v0.y = acc0[4 * rq + 1];
        v0.z = acc0[4 * rq + 2]; v0.w = acc0[4 * rq + 3];
        v1.x = acc1[4 * rq + 0]; v1.y = acc1[4 * rq + 1];
        v1.z = acc1[4 * rq + 2]; v1.w = acc1[4 * rq + 3];
        const int off = 16 * (rq >> 1) + 8 * h + 4 * (rq & 1);
        *(float4*)(orow + off)      = v0;
        *(float4*)(orow + 32 + off) = v1;
    }
}

extern "C" void kernel_launch(void* const* d_in, const int* in_sizes, int n_in,
                              void* d_out, int out_size, void* d_ws, size_t ws_size,
                              hipStream_t stream) {
    const float* feat = (const float*)d_in[0];
    // d_in[1] = points, d_in[2] = nuv — dead inputs
    const float* W0 = (const float*)d_in[3];
    const float* b0 = (const float*)d_in[4];
    const float* W1 = (const float*)d_in[5];
    const float* b1 = (const float*)d_in[6];
    const float* W2 = (const float*)d_in[7];
    const float* b2 = (const float*)d_in[8];
    float* out = (float*)d_out;
    uint4* wsA = (uint4*)d_ws;   // 12288 * 16B = 192 KiB of scratch

    prep_weights<<<48, 256, 0, stream>>>(W0, W1, W2, wsA);

    const int grid = (NTILE + WPB - 1) / WPB;
    mlp12_mfma<<<grid, BLK, 0, stream>>>(feat, wsA, b0, b1, b2, out);
}

// Round 2
// 343.446 us; speedup vs baseline: 1.2925x; 1.2925x over previous
//
#include <hip/hip_runtime.h>
#include <stdint.h>

#define CH 64
#define NPTS 500000
#define NTILE (NPTS / 32)      // 15625 point-tiles of 32
#define NSTEP 12
#define BLK 256
#define WPB (BLK / 64)         // waves per block

typedef float floatx16 __attribute__((ext_vector_type(16)));
typedef __bf16 bf16x8 __attribute__((ext_vector_type(8)));

// pack two fp32 into (bf16(even) | bf16(odd)<<16) by byte-perm truncation
__device__ __forceinline__ unsigned pk(float odd, float even) {
    return __builtin_amdgcn_perm(__float_as_uint(odd), __float_as_uint(even), 0x07060302u);
}
// top-16-bit truncation of x as a float (the "hi" bf16 part, exactly representable)
__device__ __forceinline__ float hif(float x) {
    return __uint_as_float(__float_as_uint(x) & 0xffff0000u);
}

struct U16 { unsigned a, b, c, d; };
__device__ __forceinline__ bf16x8 asb4(unsigned x0, unsigned x1, unsigned x2, unsigned x3) {
    U16 t{x0, x1, x2, x3};
    return __builtin_bit_cast(bf16x8, t);
}
__device__ __forceinline__ bf16x8 asbu4(uint4 v) {
    return __builtin_bit_cast(bf16x8, v);
}

// async global->LDS, 16B per lane; lds ptr must be wave-uniform (HW scatters +lane*16)
typedef __attribute__((address_space(3))) void lds_void;
typedef const __attribute__((address_space(1))) void gm_void;
__device__ __forceinline__ void gload_lds16(const void* g, void* l) {
    __builtin_amdgcn_global_load_lds((gm_void*)g, (lds_void*)l, 16, 0, 0);
}

// ---------------------------------------------------------------------------
// Prep kernel: W[step][k][c_out] -> bf16 hi/lo A-fragments with the bit2<->bit3
// column permutation, in lane-contiguous per-step 16 KB groups.
// flat uint4 idx = s*1024 + ((pl*2+mt)*4+q)*64 + lane
// ---------------------------------------------------------------------------
__global__ void prep_weights(const float* __restrict__ W0,
                             const float* __restrict__ W1,
                             const float* __restrict__ W2,
                             uint4* __restrict__ wsA) {
    const int g  = blockIdx.x * blockDim.x + threadIdx.x;   // 0..12287
    const int mp = g & 31;
    const int h  = (g >> 5) & 1;
    const int q  = (g >> 6) & 3;
    const int mt = (g >> 8) & 1;
    const int pl = (g >> 9) & 1;
    const int s  = g >> 10;
    const float* Wb = (s % 3 == 0) ? W0 : ((s % 3 == 1) ? W1 : W2);
    const float* Ws = Wb + (s / 3) * CH * CH;
    const int m   = mt * 32 + mp;
    const int col = (m & ~12) | ((m & 4) << 1) | ((m & 8) >> 1);  // swap bits 2,3
    unsigned o[4];
    #pragma unroll
    for (int d = 0; d < 4; ++d) {
        float e = Ws[(16 * q + 8 * h + 2 * d) * CH + col];
        float v = Ws[(16 * q + 8 * h + 2 * d + 1) * CH + col];
        if (pl) { e = e - hif(e); v = v - hif(v); }   // lo plane
        o[d] = pk(v, e);
    }
    wsA[g] = make_uint4(o[0], o[1], o[2], o[3]);
}

// ---------------------------------------------------------------------------
// Main kernel: one wave = 32 points, register-resident 12-GEMM chain.
// Weights double-buffered in LDS (2 x 16 KB), staged via global_load_lds,
// read as ds_read_b128. One barrier per step.
// launch_bounds(256,4): (256,5) spills ~300 MB to scratch (round-1 post-mortem).
// Entry stagger: co-resident blocks otherwise run lockstep (identical timing,
// per-step barriers) -> MFMA/VALU/LDS phases serialize across the whole CU
// (measured sum-of-pipes: 38%+30%+~30%). Desync by ~512cy * phase so the CU
// always has a mix of phases; setprio then favors MFMA-phase waves.
// ---------------------------------------------------------------------------
__global__ __launch_bounds__(BLK, 4) void mlp12_mfma(
    const float* __restrict__ feat,
    const uint4* __restrict__ wsA,
    const float* __restrict__ b0,
    const float* __restrict__ b1,
    const float* __restrict__ b2,
    float* __restrict__ out)
{
    __shared__ uint4 sA[2][1024];   // 2 x 16 KB weight-fragment buffers

    // phase key differs for consecutive blockIdx AND stride-256 blockIdx
    // (dispatch->CU mapping is undefined; cover both contiguous and round-robin)
    {
        const int phase = ((blockIdx.x >> 8) + blockIdx.x) & 3;
        for (int i = 0; i < phase; ++i) __builtin_amdgcn_s_sleep(8);  // ~512 cy each
    }

    const int tid  = threadIdx.x;
    const int lane = tid & 63;
    const int wv   = tid >> 6;
    int wid = blockIdx.x * WPB + wv;
    if (wid > NTILE - 1) wid = NTILE - 1;   // tail waves redo last tile (benign, no divergence at barriers)
    const int n = lane & 31;       // point within tile (MFMA col)
    const int h = lane >> 5;       // half-wave = k/channel bit3
    const size_t row = (size_t)(wid * 32 + n) * CH;

    // feature loads first (HBM latency overlaps staging prologue)
    float4 fa[4], fb[4];
    {
        const float* frow = feat + row + 8 * h;
        #pragma unroll
        for (int q = 0; q < 4; ++q) {
            fa[q] = *(const float4*)(frow + 16 * q);
            fb[q] = *(const float4*)(frow + 16 * q + 4);
        }
    }

    // stage step-0 fragments into sA[0]: each thread issues 4 x 16B DMA
    {
        const char* g = (const char*)wsA;
        #pragma unroll
        for (int c = 0; c < 4; ++c)
            gload_lds16(g + (wv * 4 + c) * 1024 + lane * 16,
                        (char*)&sA[0][0] + (wv * 4 + c) * 1024);
    }
    __syncthreads();   // drains vmcnt -> sA[0] ready

    unsigned Bhi[4][4], Blo[4][4];
    floatx16 acc0, acc1;

    #pragma unroll
    for (int s = 0; s < NSTEP; ++s) {
        const int b = s & 1;

        // prefetch step s+1 into the buffer freed by the previous barrier
        if (s + 1 < NSTEP) {
            const char* g = (const char*)wsA + (size_t)(s + 1) * 16384;
            #pragma unroll
            for (int c = 0; c < 4; ++c)
                gload_lds16(g + (wv * 4 + c) * 1024 + lane * 16,
                            (char*)&sA[1 - b][0] + (wv * 4 + c) * 1024);
        }

        const uint4* base = &sA[b][0];

        // issue first A chunk (q=0) early: ds_read latency hides under B-build VALU
        uint4 Acur[4], Anx[4];
        #pragma unroll
        for (int t = 0; t < 4; ++t) Acur[t] = base[(t * 4 + 0) * 64 + lane];

        // ---- build B fragments (features at s==0, else prev accs)
        if (s == 0) {
            #pragma unroll
            for (int q = 0; q < 4; ++q) {
                float e0 = fa[q].x, o0 = fa[q].y, e1 = fa[q].z, o1 = fa[q].w;
                float e2 = fb[q].x, o2 = fb[q].y, e3 = fb[q].z, o3 = fb[q].w;
                Bhi[q][0] = pk(o0, e0); Bhi[q][1] = pk(o1, e1);
                Bhi[q][2] = pk(o2, e2); Bhi[q][3] = pk(o3, e3);
                Blo[q][0] = pk(o0 - hif(o0), e0 - hif(e0));
                Blo[q][1] = pk(o1 - hif(o1), e1 - hif(e1));
                Blo[q][2] = pk(o2 - hif(o2), e2 - hif(e2));
                Blo[q][3] = pk(o3 - hif(o3), e3 - hif(e3));
            }
        } else {
            const bool relu = (s % 3 == 2);  // prev step had ReLU
            #pragma unroll
            for (int q = 0; q < 4; ++q) {
                const int rr = q & 1;
                #pragma unroll
                for (int d = 0; d < 4; ++d) {
                    float e, o;
                    if (q < 2) { e = acc0[8 * rr + 2 * d]; o = acc0[8 * rr + 2 * d + 1]; }
                    else       { e = acc1[8 * rr + 2 * d]; o = acc1[8 * rr + 2 * d + 1]; }
                    if (relu) { e = fmaxf(e, 0.f); o = fmaxf(o, 0.f); }
                    Bhi[q][d] = pk(o, e);
                    Blo[q][d] = pk(o - hif(o), e - hif(e));
                }
            }
        }

        // ---- init accumulators with bias (loads L2-hit; short live range)
        {
            const float* bs = ((s % 3 == 0) ? b0 : (s % 3 == 1) ? b1 : b2) + (s / 3) * CH;
            #pragma unroll
            for (int rq = 0; rq < 4; ++rq) {
                const int off = 16 * (rq >> 1) + 8 * h + 4 * (rq & 1);
                float4 v0 = *(const float4*)(bs + off);
                float4 v1 = *(const float4*)(bs + 32 + off);
                acc0[4 * rq + 0] = v0.x; acc0[4 * rq + 1] = v0.y;
                acc0[4 * rq + 2] = v0.z; acc0[4 * rq + 3] = v0.w;
                acc1[4 * rq + 0] = v1.x; acc1[4 * rq + 1] = v1.y;
                acc1[4 * rq + 2] = v1.z; acc1[4 * rq + 3] = v1.w;
            }
        }

        // ---- 24 MFMAs: hi*hi + lo_w*hi_x + hi_w*lo_x; A chunks pipelined via LDS
        #pragma unroll
        for (int q = 0; q < 4; ++q) {
            if (q < 3) {
                #pragma unroll
                for (int t = 0; t < 4; ++t) Anx[t] = base[(t * 4 + q + 1) * 64 + lane];
            }
            bf16x8 bh = asb4(Bhi[q][0], Bhi[q][1], Bhi[q][2], Bhi[q][3]);
            bf16x8 bl = asb4(Blo[q][0], Blo[q][1], Blo[q][2], Blo[q][3]);
            __builtin_amdgcn_s_setprio(1);
            acc0 = __builtin_amdgcn_mfma_f32_32x32x16_bf16(asbu4(Acur[0]), bh, acc0, 0, 0, 0);
            acc1 = __builtin_amdgcn_mfma_f32_32x32x16_bf16(asbu4(Acur[1]), bh, acc1, 0, 0, 0);
            acc0 = __builtin_amdgcn_mfma_f32_32x32x16_bf16(asbu4(Acur[2]), bh, acc0, 0, 0, 0);
            acc1 = __builtin_amdgcn_mfma_f32_32x32x16_bf16(asbu4(Acur[3]), bh, acc1, 0, 0, 0);
            acc0 = __builtin_amdgcn_mfma_f32_32x32x16_bf16(asbu4(Acur[0]), bl, acc0, 0, 0, 0);
            acc1 = __builtin_amdgcn_mfma_f32_32x32x16_bf16(asbu4(Acur[1]), bl, acc1, 0, 0, 0);
            __builtin_amdgcn_s_setprio(0);
            #pragma unroll
            for (int t = 0; t < 4; ++t) Acur[t] = Anx[t];
        }

        __syncthreads();  // all waves done with sA[b]; prefetch of s+1 drained
    }

    // ---- store step-11 output; un-permute C row rho -> channel pi(rho)
    float* orow = out + row;
    #pragma unroll
    for (int rq = 0; rq < 4; ++rq) {
        float4 v0, v1;
        v0.x = acc0[4 * rq + 0]; v0.y = acc0[4 * rq + 1];
        v0.z = acc0[4 * rq + 2]; v0.w = acc0[4 * rq + 3];
        v1.x = acc1[4 * rq + 0]; v1.y = acc1[4 * rq + 1];
        v1.z = acc1[4 * rq + 2]; v1.w = acc1[4 * rq + 3];
        const int off = 16 * (rq >> 1) + 8 * h + 4 * (rq & 1);
        *(float4*)(orow + off)      = v0;
        *(float4*)(orow + 32 + off) = v1;
    }
}

extern "C" void kernel_launch(void* const* d_in, const int* in_sizes, int n_in,
                              void* d_out, int out_size, void* d_ws, size_t ws_size,
                              hipStream_t stream) {
    const float* feat = (const float*)d_in[0];
    // d_in[1] = points, d_in[2] = nuv — dead inputs
    const float* W0 = (const float*)d_in[3];
    const float* b0 = (const float*)d_in[4];
    const float* W1 = (const float*)d_in[5];
    const float* b1 = (const float*)d_in[6];
    const float* W2 = (const float*)d_in[7];
    const float* b2 = (const float*)d_in[8];
    float* out = (float*)d_out;
    uint4* wsA = (uint4*)d_ws;   // 12288 * 16B = 192 KiB of scratch

    prep_weights<<<48, 256, 0, stream>>>(W0, W1, W2, wsA);

    const int grid = (NTILE + WPB - 1) / WPB;
    mlp12_mfma<<<grid, BLK, 0, stream>>>(feat, wsA, b0, b1, b2, out);
}